// Round 1
// baseline (2008.974 us; speedup 1.0000x reference)
//
#include <hip/hip_runtime.h>
#include <stdint.h>

// ---- types ----
typedef __bf16  bf16x8 __attribute__((ext_vector_type(8)));
typedef unsigned short u16x8 __attribute__((ext_vector_type(8)));
typedef float   f32x4  __attribute__((ext_vector_type(4)));

#define LDP 72   // 64 + 8 bf16 pad -> row stride 144 B -> 2-way bank alias only (free)

__device__ __forceinline__ unsigned short f2b(float f) {
  union { float f; uint32_t u; } v; v.f = f;
  uint32_t r = v.u + 0x7fffu + ((v.u >> 16) & 1u);   // RNE
  return (unsigned short)(r >> 16);
}
__device__ __forceinline__ float b2f(unsigned short u) {
  union { uint32_t u; float f; } v; v.u = ((uint32_t)u) << 16;
  return v.f;
}

// ---- common 128x128-tile bf16 MFMA GEMM: C = A[M,K] @ Bt[N,K]^T ----
// 256 threads = 4 waves in 2x2; each wave 64x64 via 4x4 grid of 16x16x32 MFMA.
// A/B fragment: lane holds elem[k = (lane>>4)*8 + j] of row (lane&15)  (m89/m91-verified)
// C/D: col = lane&15, row = (lane>>4)*4 + reg
template <class Epi>
__device__ __forceinline__ void gemm_core(
    const unsigned short* __restrict__ A, int lda,
    const unsigned short* __restrict__ Bt, int ldb,
    int K, int r0, int c0, Epi epi)
{
  extern __shared__ unsigned short lds[];
  unsigned short* As = lds;             // [128][LDP]
  unsigned short* Bs = lds + 128 * LDP; // [128][LDP]
  const int tid  = threadIdx.x;
  const int lane = tid & 63;
  const int wave = tid >> 6;
  const int wr   = (wave >> 1) * 64;
  const int wc   = (wave & 1) * 64;
  const int quad = lane >> 4;
  const int lm   = lane & 15;

  f32x4 acc[4][4];
#pragma unroll
  for (int i = 0; i < 4; i++)
#pragma unroll
    for (int j = 0; j < 4; j++)
      acc[i][j] = (f32x4){0.f, 0.f, 0.f, 0.f};

  for (int k0 = 0; k0 < K; k0 += 64) {
    __syncthreads();
#pragma unroll
    for (int s = 0; s < 4; s++) {
      int chunk = tid + s * 256;      // 1024 chunks of 8 bf16 per tile
      int row   = chunk >> 3;
      int kk    = (chunk & 7) << 3;
      f32x4 va = *(const f32x4*)&A[(size_t)(r0 + row) * lda + k0 + kk];
      *(f32x4*)&As[row * LDP + kk] = va;
      f32x4 vb = *(const f32x4*)&Bt[(size_t)(c0 + row) * ldb + k0 + kk];
      *(f32x4*)&Bs[row * LDP + kk] = vb;
    }
    __syncthreads();
#pragma unroll
    for (int kk = 0; kk < 64; kk += 32) {
      bf16x8 a[4], b[4];
#pragma unroll
      for (int i = 0; i < 4; i++)
        a[i] = *(const bf16x8*)&As[(wr + i * 16 + lm) * LDP + kk + quad * 8];
#pragma unroll
      for (int j = 0; j < 4; j++)
        b[j] = *(const bf16x8*)&Bs[(wc + j * 16 + lm) * LDP + kk + quad * 8];
#pragma unroll
      for (int i = 0; i < 4; i++)
#pragma unroll
        for (int j = 0; j < 4; j++)
          acc[i][j] = __builtin_amdgcn_mfma_f32_16x16x32_bf16(a[i], b[j], acc[i][j], 0, 0, 0);
    }
  }
#pragma unroll
  for (int i = 0; i < 4; i++)
#pragma unroll
    for (int j = 0; j < 4; j++)
#pragma unroll
      for (int r = 0; r < 4; r++)
        epi(r0 + wr + i * 16 + quad * 4 + r, c0 + wc + j * 16 + lm, acc[i][j][r]);
}

// ---- conversion kernels ----
__global__ __launch_bounds__(256) void cvt_bf16_kernel(const float* __restrict__ in,
                                                       unsigned short* __restrict__ out) {
  size_t i = ((size_t)blockIdx.x * 256 + threadIdx.x) * 8;
  f32x4 a = *(const f32x4*)&in[i];
  f32x4 b = *(const f32x4*)&in[i + 4];
  u16x8 r;
  r[0] = f2b(a[0]); r[1] = f2b(a[1]); r[2] = f2b(a[2]); r[3] = f2b(a[3]);
  r[4] = f2b(b[0]); r[5] = f2b(b[1]); r[6] = f2b(b[2]); r[7] = f2b(b[3]);
  *(u16x8*)&out[i] = r;
}

// transpose+convert: in fp32 [R,C] (z slices) -> out bf16 [C,R]
__global__ __launch_bounds__(256) void tconv_kernel(const float* __restrict__ in,
                                                    unsigned short* __restrict__ out,
                                                    int R, int C) {
  __shared__ unsigned short tile[32][33];
  int r0 = blockIdx.y * 32, c0 = blockIdx.x * 32;
  const float* inz = in + (size_t)blockIdx.z * R * C;
  unsigned short* outz = out + (size_t)blockIdx.z * R * C;
  int tr = threadIdx.x >> 5;
  int tc = threadIdx.x & 31;
#pragma unroll
  for (int s = 0; s < 4; s++) {
    int r = tr + s * 8;
    tile[r][tc] = f2b(inz[(size_t)(r0 + r) * C + c0 + tc]);
  }
  __syncthreads();
#pragma unroll
  for (int s = 0; s < 4; s++) {
    int r = tr + s * 8;
    outz[(size_t)(c0 + r) * R + r0 + tc] = tile[tc][r];
  }
}

// ---- stage kernels ----
// z = p*8+h, p in {q,k,v}. q/k: [H][B*T][HD]; v stored transposed: vt[(h*16+b)][d][t]
__global__ __launch_bounds__(256) void proj_kernel(const unsigned short* __restrict__ data,
                                                   const unsigned short* __restrict__ Wt,
                                                   unsigned short* __restrict__ q,
                                                   unsigned short* __restrict__ k,
                                                   unsigned short* __restrict__ vt) {
  int z = blockIdx.z;
  int p = z >> 3, h = z & 7;
  int r0 = blockIdx.y * 128, c0 = blockIdx.x * 128;
  const unsigned short* Bt = Wt + (size_t)z * 512 * 4096;
  if (p == 0) {
    unsigned short* dst = q + (size_t)h * 8192 * 512;
    gemm_core(data, 4096, Bt, 4096, 4096, r0, c0,
              [=](int row, int col, float v) { dst[(size_t)row * 512 + col] = f2b(v); });
  } else if (p == 1) {
    unsigned short* dst = k + (size_t)h * 8192 * 512;
    gemm_core(data, 4096, Bt, 4096, 4096, r0, c0,
              [=](int row, int col, float v) { dst[(size_t)row * 512 + col] = f2b(v); });
  } else {
    gemm_core(data, 4096, Bt, 4096, 4096, r0, c0,
              [=](int row, int col, float v) {
                // b = row>>9, t = row&511
                vt[(((size_t)(h * 16 + (row >> 9)) * 512 + col) << 9) + (row & 511)] = f2b(v);
              });
  }
}

// z = h*16+b. S[z][t][s] = (q . k) / 64, fully-masked tiles skipped.
__global__ __launch_bounds__(256) void score_kernel(const unsigned short* __restrict__ q,
                                                    const unsigned short* __restrict__ k,
                                                    unsigned short* __restrict__ S) {
  int z = blockIdx.z;
  int h = z >> 4, b = z & 15;
  int r0 = blockIdx.y * 128, c0 = blockIdx.x * 128;
  if (c0 > r0 + 127) return;  // fully above diagonal
  const unsigned short* A  = q + ((size_t)h * 8192 + b * 512) * 512;
  const unsigned short* Bt = k + ((size_t)h * 8192 + b * 512) * 512;
  unsigned short* Sz = S + (size_t)z * 262144;
  gemm_core(A, 512, Bt, 512, 512, r0, c0,
            [=](int row, int col, float v) { Sz[(size_t)row * 512 + col] = f2b(v * 0.015625f); });
}

// one wave per row of 512; masked (s>t) -> 0 written
__global__ __launch_bounds__(256) void softmax_kernel(unsigned short* __restrict__ S) {
  int row  = blockIdx.x * 4 + (threadIdx.x >> 6);  // global row in [0, 128*512)
  int lane = threadIdx.x & 63;
  int t = row & 511;
  unsigned short* pr = S + (size_t)row * 512;
  u16x8 u = *(const u16x8*)&pr[lane * 8];
  float s[8];
  float m = -1e30f;
#pragma unroll
  for (int jj = 0; jj < 8; jj++) {
    int j = lane * 8 + jj;
    s[jj] = (j <= t) ? b2f(u[jj]) : -1e30f;
    m = fmaxf(m, s[jj]);
  }
#pragma unroll
  for (int o = 32; o > 0; o >>= 1) m = fmaxf(m, __shfl_xor(m, o, 64));
  float l = 0.f;
#pragma unroll
  for (int jj = 0; jj < 8; jj++) {
    int j = lane * 8 + jj;
    s[jj] = (j <= t) ? __expf(s[jj] - m) : 0.f;
    l += s[jj];
  }
#pragma unroll
  for (int o = 32; o > 0; o >>= 1) l += __shfl_xor(l, o, 64);
  float inv = 1.f / l;
  u16x8 r;
#pragma unroll
  for (int jj = 0; jj < 8; jj++) r[jj] = f2b(s[jj] * inv);
  *(u16x8*)&pr[lane * 8] = r;
}

// out[b][t][h*512+d] = P @ V ; K trimmed to causal bound (P zeros beyond t anyway)
__global__ __launch_bounds__(256) void av_kernel(const unsigned short* __restrict__ S,
                                                 const unsigned short* __restrict__ vt,
                                                 unsigned short* __restrict__ ao) {
  int z = blockIdx.z;
  int h = z >> 4, b = z & 15;
  int r0 = blockIdx.y * 128, c0 = blockIdx.x * 128;
  const unsigned short* A  = S + (size_t)z * 262144;
  const unsigned short* Bt = vt + (size_t)z * 262144;
  int K = r0 + 128;  // multiple of 64
  gemm_core(A, 512, Bt, 512, K, r0, c0,
            [=](int row, int col, float v) {
              ao[((size_t)(b * 512 + row)) * 4096 + h * 512 + col] = f2b(v);
            });
}

__global__ __launch_bounds__(256) void out_kernel(const unsigned short* __restrict__ ao,
                                                  const unsigned short* __restrict__ Wot,
                                                  const float* __restrict__ bo,
                                                  float* __restrict__ out) {
  int r0 = blockIdx.y * 128, c0 = blockIdx.x * 128;
  gemm_core(ao, 4096, Wot, 4096, 4096, r0, c0,
            [=](int row, int col, float v) { out[(size_t)row * 4096 + col] = v + bo[col]; });
}

// ---- launch ----
extern "C" void kernel_launch(void* const* d_in, const int* in_sizes, int n_in,
                              void* d_out, int out_size, void* d_ws, size_t ws_size,
                              hipStream_t stream) {
  const float* data = (const float*)d_in[0];
  const float* Wq = (const float*)d_in[1];
  const float* Wk = (const float*)d_in[2];
  const float* Wv = (const float*)d_in[3];
  const float* Wo = (const float*)d_in[4];
  const float* bo = (const float*)d_in[5];
  float* out = (float*)d_out;

  // workspace layout (bytes); total 402,653,184 (384 MB)
  char* w = (char*)d_ws;
  unsigned short* datab = (unsigned short*)(w);                   // 64 MB  [8192][4096] bf16
  unsigned short* Wt    = (unsigned short*)(w + 67108864ULL);     // 96 MB  [24][512][4096] bf16
  unsigned short* Wot   = (unsigned short*)(w + 167772160ULL);    // 32 MB  [4096][4096] bf16
  unsigned short* qb    = (unsigned short*)(w + 201326592ULL);    // 64 MB  [8][8192][512]
  unsigned short* kb    = (unsigned short*)(w + 268435456ULL);    // 64 MB
  unsigned short* vtb   = (unsigned short*)(w + 335544320ULL);    // 64 MB  [128][512][512]
  unsigned short* Sb    = Wt;     // reuse: weights no longer needed after proj
  unsigned short* aob   = datab;  // reuse: data no longer needed after proj

  cvt_bf16_kernel<<<16384, 256, 0, stream>>>(data, datab);
  tconv_kernel<<<dim3(16, 128, 8), 256, 0, stream>>>(Wq, Wt, 4096, 512);
  tconv_kernel<<<dim3(16, 128, 8), 256, 0, stream>>>(Wk, Wt + (size_t)8 * 2097152, 4096, 512);
  tconv_kernel<<<dim3(16, 128, 8), 256, 0, stream>>>(Wv, Wt + (size_t)16 * 2097152, 4096, 512);
  tconv_kernel<<<dim3(128, 128, 1), 256, 0, stream>>>(Wo, Wot, 4096, 4096);

  proj_kernel<<<dim3(4, 64, 24), 256, 36864, stream>>>(datab, Wt, qb, kb, vtb);
  score_kernel<<<dim3(4, 4, 128), 256, 36864, stream>>>(qb, kb, Sb);
  softmax_kernel<<<16384, 256, 0, stream>>>(Sb);
  av_kernel<<<dim3(4, 4, 128), 256, 36864, stream>>>(Sb, vtb, aob);
  out_kernel<<<dim3(32, 64, 1), 256, 36864, stream>>>(aob, Wot, bo, out);
}

// Round 2
// 1644.861 us; speedup vs baseline: 1.2214x; 1.2214x over previous
//
#include <hip/hip_runtime.h>
#include <stdint.h>

// ---- types ----
typedef __bf16  bf16x8 __attribute__((ext_vector_type(8)));
typedef unsigned short u16x8 __attribute__((ext_vector_type(8)));
typedef float   f32x4  __attribute__((ext_vector_type(4)));

__device__ __forceinline__ unsigned short f2b(float f) {
  union { float f; uint32_t u; } v; v.f = f;
  uint32_t r = v.u + 0x7fffu + ((v.u >> 16) & 1u);   // RNE
  return (unsigned short)(r >> 16);
}
__device__ __forceinline__ float b2f(unsigned short u) {
  union { uint32_t u; float f; } v; v.u = ((uint32_t)u) << 16;
  return v.f;
}

// async global->LDS, 16B per lane, wave-uniform LDS base (lane i lands at base+i*16)
#define GLDS16(gp, lp) __builtin_amdgcn_global_load_lds( \
    (const __attribute__((address_space(1))) void*)(gp), \
    (__attribute__((address_space(3))) void*)(lp), 16, 0, 0)

// ---- common 128x128-tile bf16 MFMA GEMM: C = A[M,K] @ Bt[N,K]^T ----
// m97 structure: global_load_lds width=16 staging, unpadded LDS [128][64] with
// XOR chunk swizzle: 16B-chunk (row, c) stored at slot c ^ (row & 7).
//  - staging: DMA layout forced (base + lane*16B); lane computes which global
//    chunk belongs at its slot -> conflict-free by construction.
//  - ds_read_b128 fragment reads: p = c ^ (lm&7) spreads the 8 lanes of each
//    quad across all 8 bank-quads -> 8-cycle minimum, no serialization.
// 4 waves in 2x2; each wave 64x64 via 4x4 grid of 16x16x32 MFMA.
// A/B frag: lane holds k = quad*8+j of row (lane&15). C/D: col=lane&15, row=quad*4+reg.
template <class Epi>
__device__ __forceinline__ void gemm_core(
    const unsigned short* __restrict__ A, int lda,
    const unsigned short* __restrict__ Bt, int ldb,
    int K, int r0, int c0, Epi epi)
{
  extern __shared__ unsigned short lds[];
  unsigned short* As = lds;            // [128][64] bf16, swizzled chunks
  unsigned short* Bs = lds + 128 * 64;
  const int tid  = threadIdx.x;
  const int lane = tid & 63;
  const int wave = tid >> 6;
  const int wr   = (wave >> 1) * 64;
  const int wc   = (wave & 1) * 64;
  const int quad = lane >> 4;
  const int lm   = lane & 15;

  // staging geometry: slot s covers chunks (wave*4+s)*64 + lane
  int srow[4], scol[4], sbase[4];
#pragma unroll
  for (int s = 0; s < 4; s++) {
    int chunk = (wave * 4 + s) * 64 + lane;
    srow[s]  = chunk >> 3;                      // tile row
    scol[s]  = ((chunk & 7) ^ (srow[s] & 7)) * 8; // global k-offset (unswizzled)
    sbase[s] = (wave * 4 + s) * 512;            // wave-uniform LDS base (elems)
  }

  f32x4 acc[4][4];
#pragma unroll
  for (int i = 0; i < 4; i++)
#pragma unroll
    for (int j = 0; j < 4; j++)
      acc[i][j] = (f32x4){0.f, 0.f, 0.f, 0.f};

  for (int k0 = 0; k0 < K; k0 += 64) {
    __syncthreads();
#pragma unroll
    for (int s = 0; s < 4; s++) {
      GLDS16(A  + (size_t)(r0 + srow[s]) * lda + k0 + scol[s], As + sbase[s]);
      GLDS16(Bt + (size_t)(c0 + srow[s]) * ldb + k0 + scol[s], Bs + sbase[s]);
    }
    __syncthreads();   // compiler emits vmcnt(0) drain before s_barrier
#pragma unroll
    for (int kk = 0; kk < 64; kk += 32) {
      bf16x8 a[4], b[4];
      const int p = (((kk >> 3) + quad) ^ (lm & 7)) * 8;  // swizzled chunk offset
#pragma unroll
      for (int i = 0; i < 4; i++)
        a[i] = *(const bf16x8*)&As[(wr + i * 16 + lm) * 64 + p];
#pragma unroll
      for (int j = 0; j < 4; j++)
        b[j] = *(const bf16x8*)&Bs[(wc + j * 16 + lm) * 64 + p];
#pragma unroll
      for (int i = 0; i < 4; i++)
#pragma unroll
        for (int j = 0; j < 4; j++)
          acc[i][j] = __builtin_amdgcn_mfma_f32_16x16x32_bf16(a[i], b[j], acc[i][j], 0, 0, 0);
    }
  }
#pragma unroll
  for (int i = 0; i < 4; i++)
#pragma unroll
    for (int j = 0; j < 4; j++)
#pragma unroll
      for (int r = 0; r < 4; r++)
        epi(r0 + wr + i * 16 + quad * 4 + r, c0 + wc + j * 16 + lm, acc[i][j][r]);
}

// ---- conversion kernels ----
__global__ __launch_bounds__(256) void cvt_bf16_kernel(const float* __restrict__ in,
                                                       unsigned short* __restrict__ out) {
  size_t i = ((size_t)blockIdx.x * 256 + threadIdx.x) * 8;
  f32x4 a = *(const f32x4*)&in[i];
  f32x4 b = *(const f32x4*)&in[i + 4];
  u16x8 r;
  r[0] = f2b(a[0]); r[1] = f2b(a[1]); r[2] = f2b(a[2]); r[3] = f2b(a[3]);
  r[4] = f2b(b[0]); r[5] = f2b(b[1]); r[6] = f2b(b[2]); r[7] = f2b(b[3]);
  *(u16x8*)&out[i] = r;
}

// transpose+convert: in fp32 [R,C] (z slices) -> out bf16 [C,R]
__global__ __launch_bounds__(256) void tconv_kernel(const float* __restrict__ in,
                                                    unsigned short* __restrict__ out,
                                                    int R, int C) {
  __shared__ unsigned short tile[32][33];
  int r0 = blockIdx.y * 32, c0 = blockIdx.x * 32;
  const float* inz = in + (size_t)blockIdx.z * R * C;
  unsigned short* outz = out + (size_t)blockIdx.z * R * C;
  int tr = threadIdx.x >> 5;
  int tc = threadIdx.x & 31;
#pragma unroll
  for (int s = 0; s < 4; s++) {
    int r = tr + s * 8;
    tile[r][tc] = f2b(inz[(size_t)(r0 + r) * C + c0 + tc]);
  }
  __syncthreads();
#pragma unroll
  for (int s = 0; s < 4; s++) {
    int r = tr + s * 8;
    outz[(size_t)(c0 + r) * R + r0 + tc] = tile[tc][r];
  }
}

// ---- stage kernels ----
// grid (4, 24, 64): x = col tile, y = z-slice (p*8+h), z = row block (slowest ->
// all 24 weight slices co-resident over the same A stripe; Wt stays L3-resident)
__global__ __launch_bounds__(256) void proj_kernel(const unsigned short* __restrict__ data,
                                                   const unsigned short* __restrict__ Wt,
                                                   unsigned short* __restrict__ q,
                                                   unsigned short* __restrict__ k,
                                                   unsigned short* __restrict__ vt) {
  int z = blockIdx.y;
  int p = z >> 3, h = z & 7;
  int r0 = blockIdx.z * 128, c0 = blockIdx.x * 128;
  const unsigned short* Bt = Wt + (size_t)z * 512 * 4096;
  if (p == 0) {
    unsigned short* dst = q + (size_t)h * 8192 * 512;
    gemm_core(data, 4096, Bt, 4096, 4096, r0, c0,
              [=](int row, int col, float v) { dst[(size_t)row * 512 + col] = f2b(v); });
  } else if (p == 1) {
    unsigned short* dst = k + (size_t)h * 8192 * 512;
    gemm_core(data, 4096, Bt, 4096, 4096, r0, c0,
              [=](int row, int col, float v) { dst[(size_t)row * 512 + col] = f2b(v); });
  } else {
    gemm_core(data, 4096, Bt, 4096, 4096, r0, c0,
              [=](int row, int col, float v) {
                // b = row>>9, t = row&511 ; v stored transposed per (h,b): [d][t]
                vt[(((size_t)(h * 16 + (row >> 9)) * 512 + col) << 9) + (row & 511)] = f2b(v);
              });
  }
}

// z = h*16+b. S[z][t][s] = (q . k) / 64, fully-masked tiles skipped.
__global__ __launch_bounds__(256) void score_kernel(const unsigned short* __restrict__ q,
                                                    const unsigned short* __restrict__ k,
                                                    unsigned short* __restrict__ S) {
  int z = blockIdx.z;
  int h = z >> 4, b = z & 15;
  int r0 = blockIdx.y * 128, c0 = blockIdx.x * 128;
  if (c0 > r0 + 127) return;  // fully above diagonal
  const unsigned short* A  = q + ((size_t)h * 8192 + b * 512) * 512;
  const unsigned short* Bt = k + ((size_t)h * 8192 + b * 512) * 512;
  unsigned short* Sz = S + (size_t)z * 262144;
  gemm_core(A, 512, Bt, 512, 512, r0, c0,
            [=](int row, int col, float v) { Sz[(size_t)row * 512 + col] = f2b(v * 0.015625f); });
}

// one wave per row of 512; masked (s>t) -> 0 written
__global__ __launch_bounds__(256) void softmax_kernel(unsigned short* __restrict__ S) {
  int row  = blockIdx.x * 4 + (threadIdx.x >> 6);  // global row in [0, 128*512)
  int lane = threadIdx.x & 63;
  int t = row & 511;
  unsigned short* pr = S + (size_t)row * 512;
  u16x8 u = *(const u16x8*)&pr[lane * 8];
  float s[8];
  float m = -1e30f;
#pragma unroll
  for (int jj = 0; jj < 8; jj++) {
    int j = lane * 8 + jj;
    s[jj] = (j <= t) ? b2f(u[jj]) : -1e30f;
    m = fmaxf(m, s[jj]);
  }
#pragma unroll
  for (int o = 32; o > 0; o >>= 1) m = fmaxf(m, __shfl_xor(m, o, 64));
  float l = 0.f;
#pragma unroll
  for (int jj = 0; jj < 8; jj++) {
    int j = lane * 8 + jj;
    s[jj] = (j <= t) ? __expf(s[jj] - m) : 0.f;
    l += s[jj];
  }
#pragma unroll
  for (int o = 32; o > 0; o >>= 1) l += __shfl_xor(l, o, 64);
  float inv = 1.f / l;
  u16x8 r;
#pragma unroll
  for (int jj = 0; jj < 8; jj++) r[jj] = f2b(s[jj] * inv);
  *(u16x8*)&pr[lane * 8] = r;
}

// out[b][t][h*512+d] = P @ V ; K trimmed to causal bound (P zeros beyond t anyway)
__global__ __launch_bounds__(256) void av_kernel(const unsigned short* __restrict__ S,
                                                 const unsigned short* __restrict__ vt,
                                                 unsigned short* __restrict__ ao) {
  int z = blockIdx.z;
  int h = z >> 4, b = z & 15;
  int r0 = blockIdx.y * 128, c0 = blockIdx.x * 128;
  const unsigned short* A  = S + (size_t)z * 262144;
  const unsigned short* Bt = vt + (size_t)z * 262144;
  int K = r0 + 128;  // multiple of 64
  gemm_core(A, 512, Bt, 512, K, r0, c0,
            [=](int row, int col, float v) {
              ao[((size_t)(b * 512 + row)) * 4096 + h * 512 + col] = f2b(v);
            });
}

__global__ __launch_bounds__(256) void out_kernel(const unsigned short* __restrict__ ao,
                                                  const unsigned short* __restrict__ Wot,
                                                  const float* __restrict__ bo,
                                                  float* __restrict__ out) {
  int r0 = blockIdx.y * 128, c0 = blockIdx.x * 128;
  gemm_core(ao, 4096, Wot, 4096, 4096, r0, c0,
            [=](int row, int col, float v) { out[(size_t)row * 4096 + col] = v + bo[col]; });
}

// ---- launch ----
extern "C" void kernel_launch(void* const* d_in, const int* in_sizes, int n_in,
                              void* d_out, int out_size, void* d_ws, size_t ws_size,
                              hipStream_t stream) {
  const float* data = (const float*)d_in[0];
  const float* Wq = (const float*)d_in[1];
  const float* Wk = (const float*)d_in[2];
  const float* Wv = (const float*)d_in[3];
  const float* Wo = (const float*)d_in[4];
  const float* bo = (const float*)d_in[5];
  float* out = (float*)d_out;

  // workspace layout (bytes); total 402,653,184 (384 MB)
  char* w = (char*)d_ws;
  unsigned short* datab = (unsigned short*)(w);                   // 64 MB  [8192][4096] bf16
  unsigned short* Wt    = (unsigned short*)(w + 67108864ULL);     // 96 MB  [24][512][4096] bf16
  unsigned short* Wot   = (unsigned short*)(w + 167772160ULL);    // 32 MB  [4096][4096] bf16
  unsigned short* qb    = (unsigned short*)(w + 201326592ULL);    // 64 MB  [8][8192][512]
  unsigned short* kb    = (unsigned short*)(w + 268435456ULL);    // 64 MB
  unsigned short* vtb   = (unsigned short*)(w + 335544320ULL);    // 64 MB  [128][512][512]
  unsigned short* Sb    = Wt;     // reuse: weights no longer needed after proj
  unsigned short* aob   = datab;  // reuse: data no longer needed after proj

  const size_t LDS_BYTES = 2 * 128 * 64 * sizeof(unsigned short);  // 32 KB

  cvt_bf16_kernel<<<16384, 256, 0, stream>>>(data, datab);
  tconv_kernel<<<dim3(16, 128, 8), 256, 0, stream>>>(Wq, Wt, 4096, 512);
  tconv_kernel<<<dim3(16, 128, 8), 256, 0, stream>>>(Wk, Wt + (size_t)8 * 2097152, 4096, 512);
  tconv_kernel<<<dim3(16, 128, 8), 256, 0, stream>>>(Wv, Wt + (size_t)16 * 2097152, 4096, 512);
  tconv_kernel<<<dim3(128, 128, 1), 256, 0, stream>>>(Wo, Wot, 4096, 4096);

  proj_kernel<<<dim3(4, 24, 64), 256, LDS_BYTES, stream>>>(datab, Wt, qb, kb, vtb);
  score_kernel<<<dim3(4, 4, 128), 256, LDS_BYTES, stream>>>(qb, kb, Sb);
  softmax_kernel<<<16384, 256, 0, stream>>>(Sb);
  av_kernel<<<dim3(4, 4, 128), 256, LDS_BYTES, stream>>>(Sb, vtb, aob);
  out_kernel<<<dim3(32, 64, 1), 256, LDS_BYTES, stream>>>(aob, Wot, bo, out);
}